// Round 6
// baseline (391.336 us; speedup 1.0000x reference)
//
#include <hip/hip_runtime.h>
#include <stdint.h>

typedef unsigned short u16;
typedef __attribute__((ext_vector_type(8))) short short8;
typedef __attribute__((ext_vector_type(4))) short short4v;
typedef __attribute__((ext_vector_type(4))) float float4v;

union V8u { short8 v; short4v h[2]; u16 u[8]; unsigned w[4]; };

__device__ __forceinline__ u16 f2bf(float f) {
  unsigned u = __float_as_uint(f);
  u = u + 0x7FFFu + ((u >> 16) & 1u);   // round-to-nearest-even
  return (u16)(u >> 16);
}
__device__ __forceinline__ float4v fzero() {
  float4v z = {0.f, 0.f, 0.f, 0.f};
  return z;
}
__device__ __forceinline__ void gl_lds16(const u16* g, u16* l) {
  __builtin_amdgcn_global_load_lds(
      (const __attribute__((address_space(1))) void*)g,
      (__attribute__((address_space(3))) void*)l, 16, 0, 0);
}

#define MFMA16(a, b, c) __builtin_amdgcn_mfma_f32_16x16x32_bf16((a), (b), (c), 0, 0, 0)

// ---------------------------------------------------------------------------
// fp32 -> bf16 for 5 contiguous segments: X (2 segs) + wq,wk,wv. 8 elems/thr.
// ---------------------------------------------------------------------------
__global__ void conv5_f32_bf16(const float* __restrict__ X,
                               const float* __restrict__ w0,
                               const float* __restrict__ w1,
                               const float* __restrict__ w2,
                               u16* __restrict__ dst, long seg) {
  const int y = blockIdx.y;
  const float* s = (y < 2) ? (X + (long)y * seg)
                           : (y == 2 ? w0 : (y == 3 ? w1 : w2));
  u16* d = dst + (long)y * seg;
  const long i = ((long)blockIdx.x * 256 + threadIdx.x) * 8;
  if (i >= seg) return;
  float4 a = *(const float4*)&s[i];
  float4 b = *(const float4*)&s[i + 4];
  V8u o;
  o.u[0] = f2bf(a.x); o.u[1] = f2bf(a.y); o.u[2] = f2bf(a.z); o.u[3] = f2bf(a.w);
  o.u[4] = f2bf(b.x); o.u[5] = f2bf(b.y); o.u[6] = f2bf(b.z); o.u[7] = f2bf(b.w);
  *(short8*)&d[i] = o.v;
}

__global__ void conv_f32_bf16(const float* __restrict__ in, u16* __restrict__ out, long n) {
  const long i = ((long)blockIdx.x * 256 + threadIdx.x) * 8;
  if (i >= n) return;
  float4 a = *(const float4*)&in[i];
  float4 b = *(const float4*)&in[i + 4];
  V8u o;
  o.u[0] = f2bf(a.x); o.u[1] = f2bf(a.y); o.u[2] = f2bf(a.z); o.u[3] = f2bf(a.w);
  o.u[4] = f2bf(b.x); o.u[5] = f2bf(b.y); o.u[6] = f2bf(b.z); o.u[7] = f2bf(b.w);
  *(short8*)&out[i] = o.v;
}

// ---------------------------------------------------------------------------
// Balanced GEMM: O[m][n] = sum_k X[m][k]*W[n][k] + bias[n].
// BM=128, BN=64*NREP, BK=64, 512 thr / 8 waves (2M x 4N), per-wave 64x(16*NREP).
//   QKV: NREP=6 (BN=384): grid 32x16 = 512 = exactly 2 balanced rounds.
//        Per-CU window: LDS reads 160x12=1920c ~ MFMA 384x4.85=1863c (balanced
//        pipes; R5's (128,256) was 1536 read vs 1242 MFMA and near-serial).
//   OP:  NREP=4 (BN=256): grid 32x8 = 256 = exactly 1 block/CU.
// LDS: lds[2][A 16KiB | B NREP*8KiB]  (NREP=6: 128 KiB; NREP=4: 96 KiB).
// Double buffer: window kt reads buf[kt&1], stages kt+1 into buf^1 (whose
//   reads all completed before the barrier that STARTED window kt). The
//   end-of-window vmcnt(0) waits loads with a FULL WINDOW (~2000cyc >> 900cyc
//   HBM) of flight -> ~free, unlike short-flight drains.
// Schedule: 4 read-groups interleaved with 4 MFMA-groups via sched_barrier(0)
//   pins, so each MFMA group runs with the next read group in flight
//   (per-wave overlap; breaks the all-waves-lockstep read phase).
// T2: byte ^= ((byte>>3)&0x70) swizzle, inverse-swizzled global source ->
//   0 bank conflicts (verified R1-R5).  T5: setprio around MFMA groups.
// T1: bijective XCD swizzle (grid % 8 == 0, cpx = grid/8).
// ---------------------------------------------------------------------------
template <int NREP, bool OUTF32>
__global__ __launch_bounds__(512, 2) void gemm_bal(
    const u16* __restrict__ X, const u16* __restrict__ Wb,
    const float* __restrict__ b0, const float* __restrict__ b1,
    const float* __restrict__ b2, void* __restrict__ Out,
    int K, int cpx)
{
  constexpr int NH = NREP / 2;
  __shared__ __align__(16) u16 lds[2][(2 + NREP) * 4096];

  const int t = threadIdx.x;            // 0..511
  const int lane = t & 63;
  const int wave = t >> 6;              // 0..7
  const int quad = lane >> 4, l16 = lane & 15;
  const int wm = wave >> 2, wn = wave & 3;   // 2 x 4 wave grid

  const int bid = (int)blockIdx.x;
  const int swz = (bid & 7) * cpx + (bid >> 3);
  const int by = swz & 31;              // 32 M-tiles of 128
  const int bx = swz >> 5;              // N-tiles of 64*NREP
  const long m0 = (long)by * 128;
  const long n0 = (long)bx * (64 * NREP);

  // staging sources (inverse-swizzled): dest d = seg*8192 + t*16 bytes,
  // logical o = d ^ ((d>>3)&0x70); row = o>>7, col elem = (o&127)>>1.
  const u16* pA[2];
  #pragma unroll
  for (int l = 0; l < 2; ++l) {
    const int d = l * 8192 + t * 16;
    const int o = d ^ ((d >> 3) & 0x70);
    pA[l] = X + (m0 + (o >> 7)) * (long)K + ((o & 127) >> 1);
  }
  const u16* pB[NREP];
  #pragma unroll
  for (int s = 0; s < NREP; ++s) {
    const int d = s * 8192 + t * 16;
    const int o = d ^ ((d >> 3) & 0x70);
    pB[s] = Wb + (n0 + (o >> 7)) * (long)K + ((o & 127) >> 1);
  }

  // per-lane swizzled ds_read byte offsets (row base added separately)
  int offk[2];
  #pragma unroll
  for (int kk = 0; kk < 2; ++kk)
    offk[kk] = l16 * 128 + ((kk * 64 + quad * 16) ^ ((l16 & 7) << 4));

  float4v acc[4][NREP];
  #pragma unroll
  for (int i = 0; i < 4; ++i)
    #pragma unroll
    for (int j = 0; j < NREP; ++j) acc[i][j] = fzero();

  auto STAGE = [&](u16* Lb, int kt_) {
    #pragma unroll
    for (int l = 0; l < 2; ++l)
      gl_lds16(pA[l] + (long)kt_ * 64, Lb + l * 4096 + t * 8);
    #pragma unroll
    for (int s = 0; s < NREP; ++s)
      gl_lds16(pB[s] + (long)kt_ * 64, Lb + 8192 + s * 4096 + t * 8);
  };

#define SB() __builtin_amdgcn_sched_barrier(0)
#define BAR() do { asm volatile("s_barrier" ::: "memory"); SB(); } while (0)

  const int NT = K >> 6;   // 32 K-tiles of 64

  // prologue: kt0 -> buf0 (cold-latency wait once)
  STAGE(&lds[0][0], 0);
  asm volatile("s_waitcnt vmcnt(0)" ::: "memory");
  BAR();

  for (int kt = 0; kt < NT; ++kt) {
    const int buf = kt & 1;
    const int nkt = (kt + 1 < NT) ? kt + 1 : NT - 1;  // tail: dummy restage
    const char* Ab = (const char*)&lds[buf][0] + wm * 8192;
    const char* Bb = (const char*)&lds[buf][8192] + wn * (16 * NREP) * 128;

    short8 a[4][2], b[NREP][2];

    STAGE(&lds[buf ^ 1][0], nkt);     // kt+1 -> other buffer (vmem, in flight)

    // R0: a kk0 + b-low kk0
    #pragma unroll
    for (int i = 0; i < 4; ++i)
      a[i][0] = *(const short8*)(Ab + i * 2048 + offk[0]);
    #pragma unroll
    for (int j = 0; j < NH; ++j)
      b[j][0] = *(const short8*)(Bb + j * 2048 + offk[0]);
    // R1: b-high kk0 + a kk1
    #pragma unroll
    for (int j = NH; j < NREP; ++j)
      b[j][0] = *(const short8*)(Bb + j * 2048 + offk[0]);
    #pragma unroll
    for (int i = 0; i < 4; ++i)
      a[i][1] = *(const short8*)(Ab + i * 2048 + offk[1]);
    SB();

    // M0: kk0 x low (needs only R0; R1 stays in flight underneath)
    __builtin_amdgcn_s_setprio(1);
    #pragma unroll
    for (int i = 0; i < 4; ++i)
      #pragma unroll
      for (int j = 0; j < NH; ++j)
        acc[i][j] = MFMA16(a[i][0], b[j][0], acc[i][j]);
    __builtin_amdgcn_s_setprio(0);
    SB();

    // R2: b-low kk1
    #pragma unroll
    for (int j = 0; j < NH; ++j)
      b[j][1] = *(const short8*)(Bb + j * 2048 + offk[1]);
    SB();

    // M1: kk0 x high
    __builtin_amdgcn_s_setprio(1);
    #pragma unroll
    for (int i = 0; i < 4; ++i)
      #pragma unroll
      for (int j = NH; j < NREP; ++j)
        acc[i][j] = MFMA16(a[i][0], b[j][0], acc[i][j]);
    __builtin_amdgcn_s_setprio(0);
    SB();

    // R3: b-high kk1
    #pragma unroll
    for (int j = NH; j < NREP; ++j)
      b[j][1] = *(const short8*)(Bb + j * 2048 + offk[1]);
    SB();

    // M2: kk1 x low
    __builtin_amdgcn_s_setprio(1);
    #pragma unroll
    for (int i = 0; i < 4; ++i)
      #pragma unroll
      for (int j = 0; j < NH; ++j)
        acc[i][j] = MFMA16(a[i][1], b[j][1], acc[i][j]);
    __builtin_amdgcn_s_setprio(0);
    SB();

    // M3: kk1 x high
    __builtin_amdgcn_s_setprio(1);
    #pragma unroll
    for (int i = 0; i < 4; ++i)
      #pragma unroll
      for (int j = NH; j < NREP; ++j)
        acc[i][j] = MFMA16(a[i][1], b[j][1], acc[i][j]);
    __builtin_amdgcn_s_setprio(0);

    // kt+1 resident (full-window flight -> ~free); all waves aligned
    asm volatile("s_waitcnt vmcnt(0)" ::: "memory");
    BAR();
  }

#undef SB
#undef BAR

  // epilogue: bias + store; segment z = col>>11 (Q/K/V or single for OP)
  #pragma unroll
  for (int j = 0; j < NREP; ++j) {
    const int cg = (int)n0 + wn * (16 * NREP) + j * 16 + l16;
    const int z = cg >> 11, col = cg & 2047;
    const float* Bp = (z == 0) ? b0 : (z == 1 ? b1 : b2);
    const float bvv = Bp[col];
    #pragma unroll
    for (int i = 0; i < 4; ++i) {
      const long r0 = m0 + wm * 64 + i * 16 + quad * 4;
      #pragma unroll
      for (int r = 0; r < 4; ++r) {
        const long off = (long)z * (4096L * 2048) + (r0 + r) * 2048 + col;
        const float v = acc[i][j][r] + bvv;
        if (OUTF32) ((float*)Out)[off] = v;
        else        ((u16*)Out)[off] = f2bf(v);
      }
    }
  }
}

// ---------------------------------------------------------------------------
// Causal flash attention, fixed-scale softmax + ones-column row-sum,
// 32 Q rows per wave / 128 Q rows per pass.
// BALANCED: grid.x = 8; block x sequentially processes Q-tile (15-x) [heavy]
// then Q-tile (x) [light] -> uniform 17 KV-tile-units per block. In-place
// Ctx-over-Qw stays safe: heavy passes write rows 1024..2047, light passes
// read rows 0..1023 (disjoint).  (unchanged this round)
// ---------------------------------------------------------------------------
#define S_LEN 2048
#define HID   2048
#define HD    128

__global__ __launch_bounds__(256, 2) void attn_fwd(
    const u16* __restrict__ Q, const u16* __restrict__ K,
    const u16* __restrict__ V, u16* __restrict__ Ctx)
{
  __shared__ u16 Ks[2][32 * 136];      // K rows natural, pad 8
  __shared__ unsigned Vt[2][128 * 17]; // Vt[c][r/2] = V[2r'][c] | V[2r'+1][c]<<16
  __shared__ u16 Ps[4 * 2 * 512];      // per-wave, per-group P round-trip

  const int t = threadIdx.x;
  const int lane = t & 63, wave = t >> 6;
  const int quad = lane >> 4, l16 = lane & 15;
  const int b = blockIdx.y >> 4, h = blockIdx.y & 15;

  const long base = (long)b * S_LEN * HID + (long)h * HD;
  const u16* Qp = Q + base;
  const u16* Kp = K + base;
  const u16* Vp = V + base;
  u16* Cp = Ctx + base;

  const int sr2 = t >> 4;          // 0..15: rows 2*sr2, 2*sr2+1 of the tile
  const int sc8 = (t & 15) * 8;    // feature col base

  short8 onesv;
  {
    V8u ou;
    #pragma unroll
    for (int j = 0; j < 8; ++j) ou.u[j] = 0x3F80;   // bf16 1.0
    onesv = ou.v;
  }
  const float SC = 0.08838834764831845f * 1.4426950408889634f; // scale*log2e

  for (int pass = 0; pass < 2; ++pass) {
    const int qb = (pass ? (int)blockIdx.x : 15 - (int)blockIdx.x) * 128;
    const int wqb = qb + wave * 32;  // wave's first Q row

    // Q fragments for both groups (A-layout: m=lane&15, k=quad*8+j)
    short8 qf[2][4];
    #pragma unroll
    for (int g = 0; g < 2; ++g) {
      const long qr = wqb + g * 16 + l16;
      #pragma unroll
      for (int kk = 0; kk < 4; ++kk)
        qf[g][kk] = *(const short8*)&Qp[qr * HID + kk * 32 + quad * 8];
    }

    float4v o[2][9];                 // per group: [0..7] d-groups, [8] row-sum
    #pragma unroll
    for (int g = 0; g < 2; ++g)
      #pragma unroll
      for (int i = 0; i < 9; ++i) o[g][i] = fzero();

    // prefetch tile 0 into regs, commit to buf 0
    short8 kr0, kr1, vv0, vv1;
    {
      const long g = (long)(2 * sr2) * HID + sc8;
      kr0 = *(const short8*)&Kp[g];
      kr1 = *(const short8*)&Kp[g + HID];
      vv0 = *(const short8*)&Vp[g];
      vv1 = *(const short8*)&Vp[g + HID];
    }
    {
      *(short8*)&Ks[0][(2 * sr2) * 136 + sc8]     = kr0;
      *(short8*)&Ks[0][(2 * sr2 + 1) * 136 + sc8] = kr1;
      V8u a, c; a.v = vv0; c.v = vv1;
      #pragma unroll
      for (int j = 0; j < 8; ++j)
        Vt[0][(sc8 + j) * 17 + sr2] = (unsigned)a.u[j] | ((unsigned)c.u[j] << 16);
    }
    __syncthreads();

    const int T = (qb + 128) >> 5;   // number of 32-row KV tiles
    for (int ti = 0; ti < T; ++ti) {
      const int kv0 = ti << 5;
      const int p = ti & 1;

      const bool more = (ti + 1 < T);
      if (more) {
        const long g = (long)(kv0 + 32 + 2 * sr2) * HID + sc8;
        kr0 = *(const short8*)&Kp[g];
        kr1 = *(const short8*)&Kp[g + HID];
        vv0 = *(const short8*)&Vp[g];
        vv1 = *(const short8*)&Vp[g + HID];
      }

      // wave-uniform activity: both groups share it (kv0, wqb 32-aligned)
      if (kv0 <= wqb) {
        // ---- S = Q . K^T for both groups (kf read once, used twice) ----
        float4v s[2][2];
        #pragma unroll
        for (int g = 0; g < 2; ++g) { s[g][0] = fzero(); s[g][1] = fzero(); }
        #pragma unroll
        for (int ni = 0; ni < 2; ++ni)
          #pragma unroll
          for (int kk = 0; kk < 4; ++kk) {
            short8 kf = *(const short8*)&Ks[p][(ni * 16 + l16) * 136 + kk * 32 + quad * 8];
            s[0][ni] = MFMA16(qf[0][kk], kf, s[0][ni]);
            s[1][ni] = MFMA16(qf[1][kk], kf, s[1][ni]);
          }

        // ---- fixed-scale exp + causal mask + P round-trip per group ----
        const int pb = wave * 1024;
        #pragma unroll
        for (int g = 0; g < 2; ++g) {
          const int qrow0 = wqb + g * 16 + quad * 4;
          #pragma unroll
          for (int r = 0; r < 4; ++r) {
            float s0 = fminf(s[g][0][r] * SC, 80.f);
            float s1 = fminf(s[g][1][r] * SC, 80.f);
            if (kv0 + l16 > qrow0 + r)      s0 = -1e30f;
            if (kv0 + 16 + l16 > qrow0 + r) s1 = -1e30f;
            Ps[pb + g * 512 + (quad * 4 + r) * 32 + l16]      = f2bf(__builtin_amdgcn_exp2f(s0));
            Ps[pb + g * 512 + (quad * 4 + r) * 32 + 16 + l16] = f2bf(__builtin_amdgcn_exp2f(s1));
          }
        }
        __threadfence_block();
        short8 pf0 = *(const short8*)&Ps[pb + l16 * 32 + quad * 8];
        short8 pf1 = *(const short8*)&Ps[pb + 512 + l16 * 32 + quad * 8];

        // ---- O += P . V (vf read once, used twice) ; ones row-sum ----
        #pragma unroll
        for (int dt = 0; dt < 8; ++dt) {
          const unsigned* vp = &Vt[p][(dt * 16 + l16) * 17 + quad * 4];
          V8u vf;
          vf.w[0] = vp[0]; vf.w[1] = vp[1]; vf.w[2] = vp[2]; vf.w[3] = vp[3];
          o[0][dt] = MFMA16(pf0, vf.v, o[0][dt]);
          o[1][dt] = MFMA16(pf1, vf.v, o[1][dt]);
        }
        o[0][8] = MFMA16(pf0, onesv, o[0][8]);
        o[1][8] = MFMA16(pf1, onesv, o[1][8]);
      }

      if (more) {
        *(short8*)&Ks[1 - p][(2 * sr2) * 136 + sc8]     = kr0;
        *(short8*)&Ks[1 - p][(2 * sr2 + 1) * 136 + sc8] = kr1;
        V8u a, c; a.v = vv0; c.v = vv1;
        #pragma unroll
        for (int j = 0; j < 8; ++j)
          Vt[1 - p][(sc8 + j) * 17 + sr2] = (unsigned)a.u[j] | ((unsigned)c.u[j] << 16);
      }
      __syncthreads();
    }

    // ---- epilogue: O / L -> ctx (merged-head layout [B*S][H]) ----
    #pragma unroll
    for (int g = 0; g < 2; ++g)
      #pragma unroll
      for (int r = 0; r < 4; ++r) {
        const float inv = 1.0f / o[g][8][r];
        const long qr = wqb + g * 16 + quad * 4 + r;
        #pragma unroll
        for (int dt = 0; dt < 8; ++dt)
          Cp[qr * HID + dt * 16 + l16] = f2bf(o[g][dt][r] * inv);
      }
  }
}

// ---------------------------------------------------------------------------
extern "C" void kernel_launch(void* const* d_in, const int* in_sizes, int n_in,
                              void* d_out, int out_size, void* d_ws, size_t ws_size,
                              hipStream_t stream) {
  const float* X  = (const float*)d_in[0];
  const float* wq = (const float*)d_in[1];
  const float* bq = (const float*)d_in[2];
  const float* wk = (const float*)d_in[3];
  const float* bk = (const float*)d_in[4];
  const float* wv = (const float*)d_in[5];
  const float* bv = (const float*)d_in[6];
  const float* wo = (const float*)d_in[7];
  const float* bo = (const float*)d_in[8];
  float* out = (float*)d_out;

  const long HSZ = 4096L * 2048;   // B*S x H
  const long WSZ = 2048L * 2048;
  // ws (bf16 elems): Qw Kw Vw (3x16.8MB) + Xb (16.8MB) + W0..W2 (3x8.4MB)
  u16* Qw = (u16*)d_ws;
  u16* Kw = Qw + HSZ;
  u16* Vw = Kw + HSZ;
  u16* Xb = Vw + HSZ;
  u16* Wb = Xb + HSZ;              // W0,W1,W2 contiguous after Xb
  u16* W0 = Wb;

  dim3 blk(256);
  // one fused conversion: X (2 segs) + wq + wk + wv into Xb..W2 (contiguous)
  conv5_f32_bf16<<<dim3((int)(WSZ / 2048), 5), blk, 0, stream>>>(X, wq, wk, wv, Xb, WSZ);

  // fused Q/K/V projections: M=4096, N=6144, K=2048.
  // BN=384 -> grid 512 = exactly 2 balanced rounds of 256.
  gemm_bal<6, false><<<dim3(512), dim3(512), 0, stream>>>(
      Xb, Wb, bq, bk, bv, Qw, 2048, 64);

  // causal flash attention (balanced heavy+light pairs); ctx in-place over Qw
  attn_fwd<<<dim3(8, 32), blk, 0, stream>>>(Qw, Kw, Vw, Qw);

  // output projection (fp32 out): BN=256 -> grid 256 = exactly 1 block/CU.
  conv_f32_bf16<<<(int)(WSZ / 2048), blk, 0, stream>>>(wo, W0, WSZ);
  gemm_bal<4, true><<<dim3(256), dim3(512), 0, stream>>>(
      Qw, W0, bo, bo, bo, out, 2048, 32);
}